// Round 11
// baseline (225.837 us; speedup 1.0000x reference)
//
#include <hip/hip_runtime.h>

#define IN_CH 128
#define OUT_CH 64
#define BN 64         // nodes per bucket
#define CAP 1280      // sparse slots per bucket (mean 1024, sigma 32 -> 8 sigma)
#define NPART 256     // partition blocks

__device__ __forceinline__ unsigned short f2bf(float f) {
    unsigned u = __float_as_uint(f);
    unsigned r = (u + 0x7FFFu + ((u >> 16) & 1u)) >> 16;   // RNE
    return (unsigned short)r;
}

// ---------- part1: fused hist + range-reservation + scatter (sparse) ----------
__global__ __launch_bounds__(1024) void k_part1(const int* __restrict__ row,
                                                const int* __restrict__ col,
                                                const float* __restrict__ ew,
                                                int* __restrict__ cnt,
                                                uint2* __restrict__ sparse,
                                                int E, int per, int nbuck) {
    __shared__ int lh[1600];
    __shared__ int cur[1600];
    int tid = threadIdx.x;
    for (int i = tid; i < nbuck; i += 1024) lh[i] = 0;
    __syncthreads();
    int e0 = blockIdx.x * per;
    int e1 = min(E, e0 + per);
    for (int e = e0 + tid; e < e1; e += 1024)
        atomicAdd(&lh[col[e] >> 6], 1);
    __syncthreads();
    for (int bin = tid; bin < nbuck; bin += 1024) {
        int c = lh[bin];
        int base = c ? atomicAdd(&cnt[bin], c) : 0;   // reserve range in bucket
        cur[bin] = bin * CAP + base;
    }
    __syncthreads();
    int lim = nbuck * CAP;
    for (int e = e0 + tid; e < e1; e += 1024) {
        int r = row[e];
        int c = col[e];
        float w = ew[e];
        int bin = c >> 6;
        int p = atomicAdd(&cur[bin], 1);
        if (p < lim)   // safety clamp (never triggers at 8 sigma)
            sparse[p] = make_uint2((unsigned)r | ((unsigned)(c & 63) << 17),
                                   __float_as_uint(w));
    }
}

// ---------- sort2: inline dbase scan + group bucket by node + deg/dis ----------
__global__ __launch_bounds__(256) void k_sort2(const uint2* __restrict__ sparse,
                                               const int* __restrict__ cnt,
                                               uint2* __restrict__ sorted2,
                                               uint2* __restrict__ startcnt,
                                               float* __restrict__ dis,
                                               int N, int nbuck) {
    __shared__ uint2 recbuf[CAP];    // 10 KB
    __shared__ int hist[BN];
    __shared__ int cur[BN];
    __shared__ float degs[BN];
    __shared__ float disl[BN];
    __shared__ int wpart[4];
    __shared__ int obase_s;

    int b = blockIdx.x;
    int tid = threadIdx.x;
    int sbase = b * CAP;

    // inline exclusive scan: obase = sum cnt[0..b)
    {
        int acc = 0;
        for (int j = tid; j < b; j += 256) acc += cnt[j];
#pragma unroll
        for (int d = 32; d >= 1; d >>= 1) acc += __shfl_xor(acc, d, 64);
        if ((tid & 63) == 0) wpart[tid >> 6] = acc;
    }
    if (tid < BN) { hist[tid] = 0; degs[tid] = 0.f; }
    __syncthreads();
    if (tid == 0) obase_s = wpart[0] + wpart[1] + wpart[2] + wpart[3];

    int m = min(cnt[b], CAP);

    // pass A: stage records + histogram + weighted degree
    for (int i = tid; i < m; i += 256) {
        uint2 r = sparse[sbase + i];
        recbuf[i] = r;
        int dl = (r.x >> 17) & 63;
        atomicAdd(&hist[dl], 1);
        atomicAdd(&degs[dl], __uint_as_float(r.y));
    }
    __syncthreads();
    int obase = obase_s;

    // single-wave inclusive scan over 64 bins
    if (tid < 64) {
        int h = hist[tid];
        int v = h;
#pragma unroll
        for (int d = 1; d < 64; d <<= 1) {
            int t = __shfl_up(v, d, 64);
            if (tid >= d) v += t;
        }
        int excl = v - h;
        cur[tid] = excl;
        float dd = degs[tid];
        float di = (dd > 0.f) ? rsqrtf(dd) : 0.f;
        disl[tid] = di;
        int node = b * BN + tid;
        if (node < N) {
            startcnt[node] = make_uint2((unsigned)(obase + excl), (unsigned)h);
            dis[node] = di;
        }
    }
    __syncthreads();

    // pass B: scatter to dense, weight pre-multiplied by dis[dst]
    for (int i = tid; i < m; i += 256) {
        uint2 r = recbuf[i];
        int dl = (r.x >> 17) & 63;
        int p = atomicAdd(&cur[dl], 1);
        float w2 = __uint_as_float(r.y) * disl[dl];
        sorted2[obase + p] = make_uint2(r.x & 0x1FFFF, __float_as_uint(w2));
    }
}

// ---------- h = dis[row] * (x @ W), bf16; xs transposed for b128 LDS reads ----------
__global__ __launch_bounds__(256) void k_gemm2(const float* __restrict__ x,
                                               const float* __restrict__ W,
                                               const float* __restrict__ dis,
                                               unsigned short* __restrict__ hb, int N) {
    __shared__ float xs[16][68];   // [k][row], stride 68 floats keeps 16B alignment
    __shared__ float Ws[16][64];   // [k][col]
    int tc = threadIdx.x & 15;
    int tr = threadIdx.x >> 4;
    int row0 = blockIdx.x * 64;

    float acc[4][4] = {};

    for (int k0 = 0; k0 < IN_CH; k0 += 16) {
        {
            int r = threadIdx.x >> 2;           // 0..63
            int cc = (threadIdx.x & 3) * 4;     // 0,4,8,12
            int gr = row0 + r;
            float4 v = make_float4(0.f, 0.f, 0.f, 0.f);
            if (gr < N) v = *(const float4*)(x + (size_t)gr * IN_CH + k0 + cc);
            xs[cc + 0][r] = v.x; xs[cc + 1][r] = v.y;
            xs[cc + 2][r] = v.z; xs[cc + 3][r] = v.w;
        }
        {
            int r = threadIdx.x >> 4;
            int cc = (threadIdx.x & 15) * 4;
            *(float4*)&Ws[r][cc] = *(const float4*)(W + (size_t)(k0 + r) * OUT_CH + cc);
        }
        __syncthreads();
#pragma unroll
        for (int kk = 0; kk < 16; ++kk) {
            float4 av = *(const float4*)&xs[kk][4 * tr];   // ds_read_b128
            float4 bv = *(const float4*)&Ws[kk][4 * tc];   // ds_read_b128
            acc[0][0] += av.x * bv.x; acc[0][1] += av.x * bv.y; acc[0][2] += av.x * bv.z; acc[0][3] += av.x * bv.w;
            acc[1][0] += av.y * bv.x; acc[1][1] += av.y * bv.y; acc[1][2] += av.y * bv.z; acc[1][3] += av.y * bv.w;
            acc[2][0] += av.z * bv.x; acc[2][1] += av.z * bv.y; acc[2][2] += av.z * bv.z; acc[2][3] += av.z * bv.w;
            acc[3][0] += av.w * bv.x; acc[3][1] += av.w * bv.y; acc[3][2] += av.w * bv.z; acc[3][3] += av.w * bv.w;
        }
        __syncthreads();
    }
#pragma unroll
    for (int i = 0; i < 4; ++i) {
        int gr = row0 + 4 * tr + i;
        if (gr < N) {
            float sc = dis[gr];
            ushort4 v;
            v.x = f2bf(acc[i][0] * sc);
            v.y = f2bf(acc[i][1] * sc);
            v.z = f2bf(acc[i][2] * sc);
            v.w = f2bf(acc[i][3] * sc);
            *(ushort4*)(hb + (size_t)gr * OUT_CH + 4 * tc) = v;
        }
    }
}

// ---------- agg5: half-wave per dst node; simple loop ----------
__global__ __launch_bounds__(256) void k_agg5(const uint2* __restrict__ sorted,
                                              const uint2* __restrict__ startcnt,
                                              const unsigned short* __restrict__ hb,
                                              const float* __restrict__ b,
                                              float* __restrict__ out, int N) {
    int hw = (blockIdx.x * 256 + threadIdx.x) >> 5;   // half-wave id = dst node
    int m = threadIdx.x & 31;                          // lane pair index
    if (hw >= N) return;
    uint2 sc = startcnt[hw];
    int e = (int)sc.x;
    int end = e + (int)sc.y;
    unsigned co = 2u * (unsigned)m;                    // channel offset

    float accx = 0.f, accy = 0.f;
    for (; e + 3 < end; e += 4) {
        uint2 p0 = sorted[e];
        uint2 p1 = sorted[e + 1];
        uint2 p2 = sorted[e + 2];
        uint2 p3 = sorted[e + 3];
        unsigned v0 = *(const unsigned*)(hb + (p0.x << 6) + co);
        unsigned v1 = *(const unsigned*)(hb + (p1.x << 6) + co);
        unsigned v2 = *(const unsigned*)(hb + (p2.x << 6) + co);
        unsigned v3 = *(const unsigned*)(hb + (p3.x << 6) + co);
        float w0 = __uint_as_float(p0.y), w1 = __uint_as_float(p1.y);
        float w2 = __uint_as_float(p2.y), w3 = __uint_as_float(p3.y);
        accx += w0 * __uint_as_float(v0 << 16);
        accy += w0 * __uint_as_float(v0 & 0xFFFF0000u);
        accx += w1 * __uint_as_float(v1 << 16);
        accy += w1 * __uint_as_float(v1 & 0xFFFF0000u);
        accx += w2 * __uint_as_float(v2 << 16);
        accy += w2 * __uint_as_float(v2 & 0xFFFF0000u);
        accx += w3 * __uint_as_float(v3 << 16);
        accy += w3 * __uint_as_float(v3 & 0xFFFF0000u);
    }
    for (; e < end; ++e) {
        uint2 p = sorted[e];
        unsigned v = *(const unsigned*)(hb + (p.x << 6) + co);
        float w = __uint_as_float(p.y);
        accx += w * __uint_as_float(v << 16);
        accy += w * __uint_as_float(v & 0xFFFF0000u);
    }
    float2 bb = *(const float2*)(b + co);
    float2 o;
    o.x = 1.f / (1.f + __expf(-(accx + bb.x)));
    o.y = 1.f / (1.f + __expf(-(accy + bb.y)));
    *(float2*)(out + ((size_t)hw << 6) + co) = o;
}

extern "C" void kernel_launch(void* const* d_in, const int* in_sizes, int n_in,
                              void* d_out, int out_size, void* d_ws, size_t ws_size,
                              hipStream_t stream) {
    const float* x   = (const float*)d_in[0];
    const int*   ei  = (const int*)d_in[1];
    const float* ew  = (const float*)d_in[2];
    const float* W   = (const float*)d_in[3];
    const float* b   = (const float*)d_in[4];
    float* out = (float*)d_out;

    const int N = in_sizes[0] / IN_CH;
    const int E = in_sizes[1] / 2;
    const int* row = ei;
    const int* col = ei + E;

    const int nbuck = (N + BN - 1) / BN;          // 1563
    const int per   = (E + NPART - 1) / NPART;    // 6250

    // ws (non-aliased hb, as R7): cnt[nbuck] | dis[N] | startcnt[N] uint2
    //   | sparse[nbuck*CAP] uint2 | sorted2[E] uint2 | hb[N*64] bf16   (~43 MB)
    char* p = (char*)d_ws;
    int*   cnt     = (int*)p;    p += (size_t)nbuck * 4;
    float* dis     = (float*)p;  p += (size_t)N * 4;
    uint2* startcnt= (uint2*)p;  p += (size_t)N * 8;
    uint2* sparse  = (uint2*)p;  p += (size_t)nbuck * CAP * 8;
    uint2* sorted2 = (uint2*)p;  p += (size_t)E * 8;
    unsigned short* hb = (unsigned short*)p;

    hipMemsetAsync(cnt, 0, (size_t)nbuck * 4, stream);

    k_part1<<<NPART, 1024, 0, stream>>>(row, col, ew, cnt, sparse, E, per, nbuck);
    k_sort2<<<nbuck, 256, 0, stream>>>(sparse, cnt, sorted2, startcnt, dis, N, nbuck);
    k_gemm2<<<(N + 63) / 64, 256, 0, stream>>>(x, W, dis, hb, N);
    k_agg5<<<((size_t)N * 32 + 255) / 256, 256, 0, stream>>>(sorted2, startcnt, hb, b, out, N);
}

// Round 12
// 210.185 us; speedup vs baseline: 1.0745x; 1.0745x over previous
//
#include <hip/hip_runtime.h>

#define IN_CH 128
#define OUT_CH 64
#define BN 64         // nodes per bucket
#define CAP 1280      // sparse slots per bucket (mean 1024, sigma 32 -> 8 sigma)
#define NPART 256     // partition blocks

__device__ __forceinline__ unsigned short f2bf(float f) {
    unsigned u = __float_as_uint(f);
    unsigned r = (u + 0x7FFFu + ((u >> 16) & 1u)) >> 16;   // RNE
    return (unsigned short)r;
}

// ---------- part1: fused hist + range-reservation + scatter (sparse) ----------
__global__ __launch_bounds__(1024) void k_part1(const int* __restrict__ row,
                                                const int* __restrict__ col,
                                                const float* __restrict__ ew,
                                                int* __restrict__ cnt,
                                                uint2* __restrict__ sparse,
                                                int E, int per, int nbuck) {
    __shared__ int lh[1600];
    __shared__ int cur[1600];
    int tid = threadIdx.x;
    for (int i = tid; i < nbuck; i += 1024) lh[i] = 0;
    __syncthreads();
    int e0 = blockIdx.x * per;
    int e1 = min(E, e0 + per);
    for (int e = e0 + tid; e < e1; e += 1024)
        atomicAdd(&lh[col[e] >> 6], 1);
    __syncthreads();
    for (int bin = tid; bin < nbuck; bin += 1024) {
        int c = lh[bin];
        int base = c ? atomicAdd(&cnt[bin], c) : 0;   // reserve range in bucket
        cur[bin] = bin * CAP + base;
    }
    __syncthreads();
    int lim = nbuck * CAP;
    for (int e = e0 + tid; e < e1; e += 1024) {
        int r = row[e];
        int c = col[e];
        float w = ew[e];
        int bin = c >> 6;
        int p = atomicAdd(&cur[bin], 1);
        if (p < lim)   // safety clamp (never triggers at 8 sigma)
            sparse[p] = make_uint2((unsigned)r | ((unsigned)(c & 63) << 17),
                                   __float_as_uint(w));
    }
}

// ---------- degdis: per-bucket weighted degree -> dis ----------
__global__ __launch_bounds__(256) void k_degdis(const uint2* __restrict__ sparse,
                                                const int* __restrict__ cnt,
                                                float* __restrict__ dis,
                                                int N, int nbuck) {
    __shared__ float degs[BN];
    int b = blockIdx.x;
    int tid = threadIdx.x;
    if (tid < BN) degs[tid] = 0.f;
    __syncthreads();
    int m = min(cnt[b], CAP);
    int sbase = b * CAP;
    for (int i = tid; i < m; i += 256) {
        uint2 r = sparse[sbase + i];
        atomicAdd(&degs[(r.x >> 17) & 63], __uint_as_float(r.y));
    }
    __syncthreads();
    if (tid < BN) {
        int node = b * BN + tid;
        if (node < N) {
            float d = degs[tid];
            dis[node] = (d > 0.f) ? rsqrtf(d) : 0.f;
        }
    }
}

// ---------- h = dis[row] * (x @ W), bf16; xs transposed for b128 LDS reads ----------
__global__ __launch_bounds__(256) void k_gemm2(const float* __restrict__ x,
                                               const float* __restrict__ W,
                                               const float* __restrict__ dis,
                                               unsigned short* __restrict__ hb, int N) {
    __shared__ float xs[16][68];   // [k][row], stride 68 floats keeps 16B alignment
    __shared__ float Ws[16][64];   // [k][col]
    int tc = threadIdx.x & 15;
    int tr = threadIdx.x >> 4;
    int row0 = blockIdx.x * 64;

    float acc[4][4] = {};

    for (int k0 = 0; k0 < IN_CH; k0 += 16) {
        {
            int r = threadIdx.x >> 2;           // 0..63
            int cc = (threadIdx.x & 3) * 4;     // 0,4,8,12
            int gr = row0 + r;
            float4 v = make_float4(0.f, 0.f, 0.f, 0.f);
            if (gr < N) v = *(const float4*)(x + (size_t)gr * IN_CH + k0 + cc);
            xs[cc + 0][r] = v.x; xs[cc + 1][r] = v.y;
            xs[cc + 2][r] = v.z; xs[cc + 3][r] = v.w;
        }
        {
            int r = threadIdx.x >> 4;
            int cc = (threadIdx.x & 15) * 4;
            *(float4*)&Ws[r][cc] = *(const float4*)(W + (size_t)(k0 + r) * OUT_CH + cc);
        }
        __syncthreads();
#pragma unroll
        for (int kk = 0; kk < 16; ++kk) {
            float4 av = *(const float4*)&xs[kk][4 * tr];   // ds_read_b128
            float4 bv = *(const float4*)&Ws[kk][4 * tc];   // ds_read_b128
            acc[0][0] += av.x * bv.x; acc[0][1] += av.x * bv.y; acc[0][2] += av.x * bv.z; acc[0][3] += av.x * bv.w;
            acc[1][0] += av.y * bv.x; acc[1][1] += av.y * bv.y; acc[1][2] += av.y * bv.z; acc[1][3] += av.y * bv.w;
            acc[2][0] += av.z * bv.x; acc[2][1] += av.z * bv.y; acc[2][2] += av.z * bv.z; acc[2][3] += av.z * bv.w;
            acc[3][0] += av.w * bv.x; acc[3][1] += av.w * bv.y; acc[3][2] += av.w * bv.z; acc[3][3] += av.w * bv.w;
        }
        __syncthreads();
    }
#pragma unroll
    for (int i = 0; i < 4; ++i) {
        int gr = row0 + 4 * tr + i;
        if (gr < N) {
            float sc = dis[gr];
            ushort4 v;
            v.x = f2bf(acc[i][0] * sc);
            v.y = f2bf(acc[i][1] * sc);
            v.z = f2bf(acc[i][2] * sc);
            v.w = f2bf(acc[i][3] * sc);
            *(ushort4*)(hb + (size_t)gr * OUT_CH + 4 * tc) = v;
        }
    }
}

// ---------- sort3: fused group-in-LDS + register aggregation + epilogue ----------
__global__ __launch_bounds__(256) void k_sort3(const uint2* __restrict__ sparse,
                                               const int* __restrict__ cnt,
                                               const float* __restrict__ dis,
                                               const unsigned short* __restrict__ hb,
                                               const float* __restrict__ bias,
                                               float* __restrict__ out,
                                               int N, int nbuck) {
    __shared__ uint2 recbuf[CAP];    // 10 KB: raw records
    __shared__ uint2 recbuf2[CAP];   // 10 KB: grouped by node
    __shared__ int hist[BN];
    __shared__ int cur[BN];
    __shared__ int starts[BN];

    int b = blockIdx.x;
    int tid = threadIdx.x;
    int sbase = b * CAP;
    int m = min(cnt[b], CAP);

    if (tid < BN) hist[tid] = 0;
    __syncthreads();

    // pass A: stage records + histogram
    for (int i = tid; i < m; i += 256) {
        uint2 r = sparse[sbase + i];
        recbuf[i] = r;
        atomicAdd(&hist[(r.x >> 17) & 63], 1);
    }
    __syncthreads();

    // single-wave inclusive scan over 64 bins
    if (tid < 64) {
        int h = hist[tid];
        int v = h;
#pragma unroll
        for (int d = 1; d < 64; d <<= 1) {
            int t = __shfl_up(v, d, 64);
            if (tid >= d) v += t;
        }
        int excl = v - h;
        cur[tid] = excl;
        starts[tid] = excl;
    }
    __syncthreads();

    // pass B: regroup into recbuf2 (LDS only)
    for (int i = tid; i < m; i += 256) {
        uint2 r = recbuf[i];
        int dl = (r.x >> 17) & 63;
        int p = atomicAdd(&cur[dl], 1);
        recbuf2[p] = make_uint2(r.x & 0x1FFFF, r.y);
    }
    __syncthreads();

    // agg: half-wave per node, records from LDS, hb gather, fused epilogue
    int hwl = tid >> 5;          // 0..7
    int lanep = tid & 31;
    unsigned co = 2u * (unsigned)lanep;
    for (int nl = hwl; nl < BN; nl += 8) {
        int node = b * BN + nl;
        if (node >= N) break;
        int e = starts[nl];
        int e1 = e + hist[nl];
        float accx = 0.f, accy = 0.f;
        for (; e + 3 < e1; e += 4) {
            uint2 p0 = recbuf2[e];
            uint2 p1 = recbuf2[e + 1];
            uint2 p2 = recbuf2[e + 2];
            uint2 p3 = recbuf2[e + 3];
            unsigned v0 = *(const unsigned*)(hb + (p0.x << 6) + co);
            unsigned v1 = *(const unsigned*)(hb + (p1.x << 6) + co);
            unsigned v2 = *(const unsigned*)(hb + (p2.x << 6) + co);
            unsigned v3 = *(const unsigned*)(hb + (p3.x << 6) + co);
            float w0 = __uint_as_float(p0.y), w1 = __uint_as_float(p1.y);
            float w2 = __uint_as_float(p2.y), w3 = __uint_as_float(p3.y);
            accx += w0 * __uint_as_float(v0 << 16);
            accy += w0 * __uint_as_float(v0 & 0xFFFF0000u);
            accx += w1 * __uint_as_float(v1 << 16);
            accy += w1 * __uint_as_float(v1 & 0xFFFF0000u);
            accx += w2 * __uint_as_float(v2 << 16);
            accy += w2 * __uint_as_float(v2 & 0xFFFF0000u);
            accx += w3 * __uint_as_float(v3 << 16);
            accy += w3 * __uint_as_float(v3 & 0xFFFF0000u);
        }
        for (; e < e1; ++e) {
            uint2 p = recbuf2[e];
            unsigned v = *(const unsigned*)(hb + (p.x << 6) + co);
            float w = __uint_as_float(p.y);
            accx += w * __uint_as_float(v << 16);
            accy += w * __uint_as_float(v & 0xFFFF0000u);
        }
        float dd = dis[node];                  // dis_dst applied at the end
        float2 bb = *(const float2*)(bias + co);
        float2 o;
        o.x = 1.f / (1.f + __expf(-(accx * dd + bb.x)));
        o.y = 1.f / (1.f + __expf(-(accy * dd + bb.y)));
        *(float2*)(out + ((size_t)node << 6) + co) = o;
    }
}

extern "C" void kernel_launch(void* const* d_in, const int* in_sizes, int n_in,
                              void* d_out, int out_size, void* d_ws, size_t ws_size,
                              hipStream_t stream) {
    const float* x   = (const float*)d_in[0];
    const int*   ei  = (const int*)d_in[1];
    const float* ew  = (const float*)d_in[2];
    const float* W   = (const float*)d_in[3];
    const float* b   = (const float*)d_in[4];
    float* out = (float*)d_out;

    const int N = in_sizes[0] / IN_CH;
    const int E = in_sizes[1] / 2;
    const int* row = ei;
    const int* col = ei + E;

    const int nbuck = (N + BN - 1) / BN;          // 1563
    const int per   = (E + NPART - 1) / NPART;    // 6250

    // ws: cnt[nbuck] | dis[N] | sparse[nbuck*CAP] uint2 | hb[N*64] bf16  (~29 MB)
    char* p = (char*)d_ws;
    int*   cnt     = (int*)p;    p += (size_t)nbuck * 4;
    float* dis     = (float*)p;  p += (size_t)N * 4;
    uint2* sparse  = (uint2*)p;  p += (size_t)nbuck * CAP * 8;
    unsigned short* hb = (unsigned short*)p;

    hipMemsetAsync(cnt, 0, (size_t)nbuck * 4, stream);

    k_part1<<<NPART, 1024, 0, stream>>>(row, col, ew, cnt, sparse, E, per, nbuck);
    k_degdis<<<nbuck, 256, 0, stream>>>(sparse, cnt, dis, N, nbuck);
    k_gemm2<<<(N + 63) / 64, 256, 0, stream>>>(x, W, dis, hb, N);
    k_sort3<<<nbuck, 256, 0, stream>>>(sparse, cnt, dis, hb, b, out, N, nbuck);
}